// Round 1
// baseline (272.100 us; speedup 1.0000x reference)
//
#include <hip/hip_runtime.h>
#include <hip/hip_bf16.h>
#include <math.h>

typedef __attribute__((ext_vector_type(4))) float f32x4;
typedef __attribute__((ext_vector_type(8))) int i32x8;
typedef __attribute__((ext_vector_type(4))) int i32x4;

#define BM 256
#define BN 256
#define BK 128
#define TEMP_INV 14.2857142857142857f   // 1/0.07
#define UNIT_SCALE 0x7f7f7f7f           // E8M0 127 -> x1.0 exact (verified)

union frag32 {
  i32x8 v8;
  struct { i32x4 lo; i32x4 hi; } s;
};

// ---- async global->LDS, 16B per lane
static __device__ inline void async16(const void* g, void* l) {
  __builtin_amdgcn_global_load_lds(
      (const __attribute__((address_space(1))) unsigned int*)g,
      (__attribute__((address_space(3))) unsigned int*)l,
      16, 0, 0);
}

// ============================================================
// Kernel 1: L2-normalize rows of A and B (D=1024), emit fp8 e4m3
// (plain row-major). Also zeroes pos/neg accumulators. (unchanged)
// ============================================================
__global__ __launch_bounds__(256) void normalize_rows(
    const float* __restrict__ a, const float* __restrict__ b,
    unsigned char* __restrict__ oa, unsigned char* __restrict__ ob,
    float* __restrict__ pos_acc, float* __restrict__ neg_acc,
    int N, int D) {
  const int blk = blockIdx.x;
  const float* in;
  unsigned char* out;
  if (blk < N) {
    in = a + (size_t)blk * D;
    out = oa + (size_t)blk * D;
    if (threadIdx.x == 0) { pos_acc[blk] = 0.f; neg_acc[blk] = 0.f; }
  } else {
    in = b + (size_t)(blk - N) * D;
    out = ob + (size_t)(blk - N) * D;
  }
  const int t = threadIdx.x;
  const float4 v = ((const float4*)in)[t];
  float ss = v.x * v.x + v.y * v.y + v.z * v.z + v.w * v.w;
#pragma unroll
  for (int m = 32; m >= 1; m >>= 1) ss += __shfl_xor(ss, m, 64);
  __shared__ float wsum[4];
  const int wave = t >> 6, lane = t & 63;
  if (lane == 0) wsum[wave] = ss;
  __syncthreads();
  const float tot = wsum[0] + wsum[1] + wsum[2] + wsum[3];
  const float inv = 1.0f / fmaxf(sqrtf(tot), 1e-12f);
  int r = __builtin_amdgcn_cvt_pk_fp8_f32(v.x * inv, v.y * inv, 0, false);
  r = __builtin_amdgcn_cvt_pk_fp8_f32(v.z * inv, v.w * inv, r, true);
  ((int*)out)[t] = r;
}

// ============================================================
// Kernel 2: fused MX-fp8 MFMA GEMM + exp epilogue.
// 256x256 tile, BK=128, 8 waves (2Mx4N), 128 KB double-buffered LDS,
// 8-phase counted-vmcnt schedule (T3+T4) + setprio (T5), keeping the
// verified 16B-slot XOR swizzle (b128 conflict floor) and the verified
// 16x16x128 f8f6f4 fragment/CD layout from the previous winner.
//
// Per K-tile (4 phases, one C-quadrant each):
//   [ds_read frags][issue 2 stage units][s_barrier][lgkmcnt(0)+SGB]
//   [setprio(1) 8x MFMA setprio(0)][(tile end: vmcnt(2))][s_barrier]
// Stage units (8 per K-tile: A0..A3,B0..B3, 64 rows each) are issued
// as their LDS region frees: A{0,2} of the CURRENT buffer restage at
// phase 2 (freed after the two qm=0 phases); the rest of the NEXT
// buffer's tile at phases 0,1,2 of the following half. vmcnt(2) at
// each tile boundary leaves exactly the 2 newest units in flight.
// Last-iteration prefetches (kt=8,9) read <=256B past nB into the
// allocated pos/neg region and are never consumed (keeps loop uniform).
// ============================================================
__global__ __launch_bounds__(512, 2) void infonce_gemm(
    const unsigned char* __restrict__ A, const unsigned char* __restrict__ B,
    const int* __restrict__ la, const int* __restrict__ lb,
    float* __restrict__ pos_acc, float* __restrict__ neg_acc, int D) {
  __shared__ __align__(16) unsigned char sA[2][BM * BK];  // 2 x 32 KB
  __shared__ __align__(16) unsigned char sB[2][BN * BK];  // 2 x 32 KB

  const int tid = threadIdx.x;
  const int lane = tid & 63;
  const int wave = tid >> 6;  // 0..7
  const int wm = wave >> 2;   // 0..1  (M half: 128 rows)
  const int wn = wave & 3;    // 0..3  (N quarter: 64 cols)
  const int row0 = blockIdx.y * BM;
  const int col0 = blockIdx.x * BN;

  // staging: one async16 per thread covers 64 rows (srow=tid>>3) x 8 slots
  const int srow = tid >> 3;                     // 0..63
  const int ssl = ((tid & 7) ^ (srow & 7)) * 16; // pre-swizzled global slot
  const unsigned char* gA0 = A + (size_t)(row0 + srow) * 1024 + ssl;
  const unsigned char* gB0 = B + (size_t)(col0 + srow) * 1024 + ssl;

  const int q = lane >> 4;    // 0..3
  const int l15 = lane & 15;  // 0..15
  const int phys0 = ((2 * q) ^ (l15 & 7)) * 16;  // loop-invariant

  f32x4 acc[8][4] = {};

// stage unit u (64 rows) of K-tile kt into buffer bf
#define SAu(bf, u, kt)                                                     \
  async16(gA0 + (size_t)(u) * 64 * 1024 + (size_t)(kt) * 128,              \
          &sA[bf][(u) * 8192 + tid * 16])
#define SBu(bf, u, kt)                                                     \
  async16(gB0 + (size_t)(u) * 64 * 1024 + (size_t)(kt) * 128,              \
          &sB[bf][(u) * 8192 + tid * 16])

// lane's 32B fragment for tile-row rr: logical slots (2q, 2q+1)
#define LOAD32(dst, bufp, rr)                                   \
  do {                                                          \
    const unsigned char* _p = (bufp) + (size_t)(rr) * BK;       \
    frag32 _f;                                                  \
    _f.s.lo = *(const i32x4*)(_p + phys0);                      \
    _f.s.hi = *(const i32x4*)(_p + (phys0 ^ 16));               \
    dst = _f.v8;                                                \
  } while (0)

#define PH_LOADA(bufp, QM)                                      \
  LOAD32(af0, bufp, wm * 128 + (QM) * 64 + 0 + l15);            \
  LOAD32(af1, bufp, wm * 128 + (QM) * 64 + 16 + l15);           \
  LOAD32(af2, bufp, wm * 128 + (QM) * 64 + 32 + l15);           \
  LOAD32(af3, bufp, wm * 128 + (QM) * 64 + 48 + l15)

#define PH_LOADB(bufp, QN)                                      \
  LOAD32(bf0, bufp, wn * 64 + (QN) * 32 + 0 + l15);             \
  LOAD32(bf1, bufp, wn * 64 + (QN) * 32 + 16 + l15)

#define MFMA1(MI, NJ, AF, BF)                                              \
  acc[MI][NJ] = __builtin_amdgcn_mfma_scale_f32_16x16x128_f8f6f4(          \
      AF, BF, acc[MI][NJ], 0, 0, 0, UNIT_SCALE, 0, UNIT_SCALE)

#define MFMA8(QM, QN)                                                      \
  __builtin_amdgcn_s_setprio(1);                                           \
  MFMA1((QM)*4 + 0, (QN)*2 + 0, af0, bf0);                                 \
  MFMA1((QM)*4 + 0, (QN)*2 + 1, af0, bf1);                                 \
  MFMA1((QM)*4 + 1, (QN)*2 + 0, af1, bf0);                                 \
  MFMA1((QM)*4 + 1, (QN)*2 + 1, af1, bf1);                                 \
  MFMA1((QM)*4 + 2, (QN)*2 + 0, af2, bf0);                                 \
  MFMA1((QM)*4 + 2, (QN)*2 + 1, af2, bf1);                                 \
  MFMA1((QM)*4 + 3, (QN)*2 + 0, af3, bf0);                                 \
  MFMA1((QM)*4 + 3, (QN)*2 + 1, af3, bf1);                                 \
  __builtin_amdgcn_s_setprio(0)

#define BARA()                                                             \
  __builtin_amdgcn_s_barrier();                                            \
  asm volatile("s_waitcnt lgkmcnt(0)" ::: "memory");                       \
  __builtin_amdgcn_sched_barrier(0)

#define BARB() __builtin_amdgcn_s_barrier()

  // ---- prologue: full K-tile 0 -> buf0; A{0,2} of K-tile 1 -> buf1
  SAu(0, 0, 0); SAu(0, 1, 0); SAu(0, 2, 0); SAu(0, 3, 0);
  SBu(0, 0, 0); SBu(0, 1, 0); SBu(0, 2, 0); SBu(0, 3, 0);
  SAu(1, 0, 1); SAu(1, 2, 1);
  asm volatile("s_waitcnt vmcnt(2)" ::: "memory");  // K-tile 0 resident
  __builtin_amdgcn_s_barrier();

  i32x8 af0, af1, af2, af3, bf0, bf1;

#pragma unroll 1
  for (int t = 0; t < 8; ++t) {   // one K-tile (BK=128) per iteration
    const int h = t & 1;          // compute buffer
    const int hs = h ^ 1;         // buffer being restaged with tile kt
    const int kt = t + 1;         // K-tile whose staging completes this iter
    unsigned char* cA = sA[h];
    unsigned char* cB = sB[h];

    // phase 0: quad (qm=0, qn=0) — reads A units {0,2}, B qn=0 rows
    PH_LOADA(cA, 0);
    PH_LOADB(cB, 0);
    SAu(hs, 1, kt); SAu(hs, 3, kt);
    BARA();
    MFMA8(0, 0);
    BARB();

    // phase 1: quad (0,1) — af reused, reads B qn=1 rows
    PH_LOADB(cB, 1);
    SBu(hs, 0, kt); SBu(hs, 1, kt);
    BARA();
    MFMA8(0, 1);
    BARB();

    // phase 2: quad (1,0) — A units {0,2} of cur buf freed after ph1,
    // so restage them (K-tile kt+1) alongside the last B units of kt.
    PH_LOADA(cA, 1);
    PH_LOADB(cB, 0);
    SBu(hs, 2, kt); SBu(hs, 3, kt);
    SAu(h, 0, kt + 1); SAu(h, 2, kt + 1);
    BARA();
    MFMA8(1, 0);
    BARB();

    // phase 3: quad (1,1). Tile boundary: K-tile kt must be resident in
    // buf hs before next iteration reads it; allow only the 2 newest
    // (A{0,2} of kt+1) to stay in flight.
    PH_LOADB(cB, 1);
    BARA();
    MFMA8(1, 1);
    asm volatile("s_waitcnt vmcnt(2)" ::: "memory");
    BARB();
  }

  // ---- epilogue: C/D layout col = lane&15, row = q*4 + reg (verified)
  int lbv[4];
#pragma unroll
  for (int nj = 0; nj < 4; nj++) lbv[nj] = lb[col0 + wn * 64 + nj * 16 + l15];

#pragma unroll
  for (int mi = 0; mi < 8; mi++) {
#pragma unroll
    for (int r = 0; r < 4; r++) {
      const int row = row0 + wm * 128 + mi * 16 + q * 4 + r;
      const int lav = la[row];
      float sneg = 0.f, spos = 0.f;
#pragma unroll
      for (int nj = 0; nj < 4; nj++) {
        float s = acc[mi][nj][r] * TEMP_INV;
        s = fminf(fmaxf(s, -50.f), 50.f);
        const float e = __expf(s);
        sneg += e;
        if (lav == lbv[nj]) spos += e;
      }
#pragma unroll
      for (int m = 8; m >= 1; m >>= 1) {
        sneg += __shfl_xor(sneg, m, 16);
        spos += __shfl_xor(spos, m, 16);
      }
      if (l15 == 0) {
        atomicAdd(&neg_acc[row], sneg);
        atomicAdd(&pos_acc[row], spos);
      }
    }
  }
}

// ============================================================
// Kernel 3: loss = mean( log(neg) - log(max(pos,1e-8)) ) (unchanged)
// ============================================================
__global__ __launch_bounds__(1024) void final_reduce(
    const float* __restrict__ pos, const float* __restrict__ neg,
    float* __restrict__ out, int N) {
  double local = 0.0;
  const int t = threadIdx.x;
  for (int i = t; i < N / 4; i += 1024) {
    const float4 p4 = ((const float4*)pos)[i];
    const float4 n4 = ((const float4*)neg)[i];
    local += (double)(logf(n4.x) - logf(fmaxf(p4.x, 1e-8f)));
    local += (double)(logf(n4.y) - logf(fmaxf(p4.y, 1e-8f)));
    local += (double)(logf(n4.z) - logf(fmaxf(p4.z, 1e-8f)));
    local += (double)(logf(n4.w) - logf(fmaxf(p4.w, 1e-8f)));
  }
#pragma unroll
  for (int m = 32; m >= 1; m >>= 1) local += __shfl_xor(local, m, 64);
  __shared__ double wsum[16];
  const int wave = t >> 6, lane = t & 63;
  if (lane == 0) wsum[wave] = local;
  __syncthreads();
  if (t == 0) {
    double tot = 0.0;
#pragma unroll
    for (int w = 0; w < 16; w++) tot += wsum[w];
    out[0] = (float)(tot / (double)N);
  }
}

extern "C" void kernel_launch(void* const* d_in, const int* in_sizes, int n_in,
                              void* d_out, int out_size, void* d_ws, size_t ws_size,
                              hipStream_t stream) {
  const float* fa = (const float*)d_in[0];
  const float* fb = (const float*)d_in[1];
  const int* la = (const int*)d_in[2];
  const int* lb = (const int*)d_in[3];

  const int D = 1024;
  const int N = in_sizes[0] / D;  // 8192
  const int M = in_sizes[1] / D;  // 8192

  unsigned char* nA = (unsigned char*)d_ws;
  unsigned char* nB = nA + (size_t)N * D;
  float* pos = (float*)(nB + (size_t)M * D);
  float* neg = pos + N;

  normalize_rows<<<N + M, 256, 0, stream>>>(fa, fb, nA, nB, pos, neg, N, D);

  dim3 grid(M / BN, N / BM);
  infonce_gemm<<<grid, 512, 0, stream>>>(nA, nB, la, lb, pos, neg, D);

  final_reduce<<<1, 1024, 0, stream>>>(pos, neg, (float*)d_out, N);
}